// Round 4
// baseline (737.284 us; speedup 1.0000x reference)
//
#include <hip/hip_runtime.h>
#include <hip/hip_fp16.h>
#include <math.h>

#define TPB 256

typedef short  bf16x8 __attribute__((ext_vector_type(8)));
typedef float  f32x4  __attribute__((ext_vector_type(4)));

__device__ __forceinline__ float gelu_erf(float x){
  return 0.5f * x * (1.0f + erff(x * 0.70710678118654752440f));
}

__device__ __forceinline__ unsigned short f2bf(float f){
  union { float f; unsigned u; } v; v.f = f;
  unsigned r = v.u + 0x7fff + ((v.u >> 16) & 1);
  return (unsigned short)(r >> 16);
}
__device__ __forceinline__ float bf2f(unsigned short h){
  union { unsigned u; float f; } v; v.u = ((unsigned)h) << 16; return v.f;
}

// ---------------- CSR build ----------------

__global__ __launch_bounds__(TPB) void deg_kernel(const int* __restrict__ dst, int* __restrict__ deg, int E){
  int i = blockIdx.x * TPB + threadIdx.x;
  if (i < E) atomicAdd(&deg[dst[i]], 1);
}

// block-local exclusive scan of deg -> row_ptr; block sums -> bsums; also dinv
__global__ __launch_bounds__(TPB) void scan1(const int* __restrict__ deg, int* __restrict__ row_ptr,
                                             int* __restrict__ bsums, float* __restrict__ dinv, int n){
  int gid = blockIdx.x * TPB + threadIdx.x;
  int v = (gid < n) ? deg[gid] : 0;
  if (gid < n) dinv[gid] = rsqrtf((float)v + 2.0f);
  int lane = threadIdx.x & 63;
  int wid  = threadIdx.x >> 6;
  int x = v;
  #pragma unroll
  for (int off = 1; off < 64; off <<= 1){
    int y = __shfl_up(x, off);
    if (lane >= off) x += y;
  }
  __shared__ int wtot[TPB/64];
  __shared__ int woff[TPB/64];
  if (lane == 63) wtot[wid] = x;
  __syncthreads();
  if (threadIdx.x == 0){
    int s = 0;
    #pragma unroll
    for (int i = 0; i < TPB/64; ++i){ woff[i] = s; s += wtot[i]; }
    bsums[blockIdx.x] = s;
  }
  __syncthreads();
  if (gid < n) row_ptr[gid] = x - v + woff[wid];
}

// parallel single-block exclusive scan of block sums (nb <= 1024)
__global__ __launch_bounds__(1024) void scan2p(int* __restrict__ bsums, int nb){
  __shared__ int tmp[1024];
  int t = threadIdx.x;
  int v = (t < nb) ? bsums[t] : 0;
  int x = v;
  tmp[t] = x;
  __syncthreads();
  #pragma unroll
  for (int off = 1; off < 1024; off <<= 1){
    int y = (t >= off) ? tmp[t - off] : 0;
    __syncthreads();
    x += y;
    tmp[t] = x;
    __syncthreads();
  }
  if (t < nb) bsums[t] = x - v;   // exclusive
}

__global__ __launch_bounds__(TPB) void scan3(int* __restrict__ row_ptr, int* __restrict__ cursor,
                                             const int* __restrict__ boffs, int n, int E){
  int gid = blockIdx.x * TPB + threadIdx.x;
  if (gid < n){
    int v = row_ptr[gid] + boffs[blockIdx.x];
    row_ptr[gid] = v;
    cursor[gid] = v;
  }
  if (gid == 0) row_ptr[n] = E;
}

__global__ __launch_bounds__(TPB) void fill_kernel(const int* __restrict__ src, const int* __restrict__ dst,
                                                   int* __restrict__ cursor, int* __restrict__ csr_src, int E){
  int i = blockIdx.x * TPB + threadIdx.x;
  if (i < E){
    int pos = atomicAdd(&cursor[dst[i]], 1);
    // Non-temporal: scattered 4B stores must not thrash per-XCD L2 with
    // partial-line dirty evictions (R3: WRITE_SIZE 105 MB = 1.6M x 64B).
    __builtin_nontemporal_store(src[i], &csr_src[pos]);
  }
}

// ---------------- W split/transpose: fp32 -> bf16 hi/lo, transposed [col][k] ----------------

__global__ __launch_bounds__(TPB) void convW_all(const float* __restrict__ W0, const float* __restrict__ W1,
                                                 const float* __restrict__ W2, const float* __restrict__ W3,
                                                 unsigned short* __restrict__ Wh, unsigned short* __restrict__ Wl){
  int gid = blockIdx.x * TPB + threadIdx.x;
  if (gid < 3*16384){
    int which = gid >> 14, idx = gid & 16383;
    int c = idx >> 7, k = idx & 127;
    const float* W = (which == 0) ? W0 : (which == 1) ? W1 : W2;
    float f = W[k*128 + c];
    unsigned short h = f2bf(f);
    unsigned short l = f2bf(f - bf2f(h));
    Wh[gid] = h; Wl[gid] = l;
  } else if (gid < 3*16384 + 48*128){
    int idx = gid - 3*16384;
    int c = idx >> 7, k = idx & 127;
    float f = (c < 40) ? W3[k*40 + c] : 0.f;
    unsigned short h = f2bf(f);
    unsigned short l = f2bf(f - bf2f(h));
    Wh[gid] = h; Wl[gid] = l;
  }
}

// ---------------- MFMA GEMM: C[N x NC] = A[N x 128] @ W[128 x NC] (+bias) ----------------

template<int NCT, int NC, bool BIAS, typename CT>
__global__ __launch_bounds__(TPB) void gemm_mfma(const float* __restrict__ A,
                                                 const unsigned short* __restrict__ Wh,
                                                 const unsigned short* __restrict__ Wl,
                                                 const float* __restrict__ bias,
                                                 CT* __restrict__ C, int n){
  int wave = threadIdx.x >> 6;
  int lane = threadIdx.x & 63;
  int q    = lane >> 4;
  int m16  = lane & 15;
  int r0   = blockIdx.x * 128 + wave * 32;

  f32x4 acc[2][NCT];
  #pragma unroll
  for (int rt = 0; rt < 2; ++rt)
    #pragma unroll
    for (int ct = 0; ct < NCT; ++ct)
      acc[rt][ct] = (f32x4){0.f, 0.f, 0.f, 0.f};

  for (int k0 = 0; k0 < 128; k0 += 32){
    bf16x8 ah[2], al[2];
    #pragma unroll
    for (int rt = 0; rt < 2; ++rt){
      int r = r0 + rt*16 + m16;
      if (r > n-1) r = n-1;
      const float* ap = A + (size_t)r*128 + k0 + q*8;
      float4 f0 = *(const float4*)(ap);
      float4 f1 = *(const float4*)(ap + 4);
      float fv[8] = {f0.x, f0.y, f0.z, f0.w, f1.x, f1.y, f1.z, f1.w};
      #pragma unroll
      for (int j = 0; j < 8; ++j){
        unsigned short h = f2bf(fv[j]);
        unsigned short l = f2bf(fv[j] - bf2f(h));
        ah[rt][j] = (short)h;
        al[rt][j] = (short)l;
      }
    }
    #pragma unroll
    for (int ct = 0; ct < NCT; ++ct){
      int c = ct*16 + m16;
      const unsigned short* ph = Wh + (size_t)c*128 + k0 + q*8;
      const unsigned short* pl = Wl + (size_t)c*128 + k0 + q*8;
      bf16x8 bh = *(const bf16x8*)ph;
      bf16x8 bl = *(const bf16x8*)pl;
      #pragma unroll
      for (int rt = 0; rt < 2; ++rt){
        acc[rt][ct] = __builtin_amdgcn_mfma_f32_16x16x32_bf16(ah[rt], bh, acc[rt][ct], 0, 0, 0);
        acc[rt][ct] = __builtin_amdgcn_mfma_f32_16x16x32_bf16(ah[rt], bl, acc[rt][ct], 0, 0, 0);
        acc[rt][ct] = __builtin_amdgcn_mfma_f32_16x16x32_bf16(al[rt], bh, acc[rt][ct], 0, 0, 0);
      }
    }
  }
  #pragma unroll
  for (int rt = 0; rt < 2; ++rt){
    #pragma unroll
    for (int ct = 0; ct < NCT; ++ct){
      int c = ct*16 + m16;
      if (c < NC){
        float bv = BIAS ? bias[c] : 0.f;
        #pragma unroll
        for (int i = 0; i < 4; ++i){
          int r = r0 + rt*16 + q*4 + i;
          if (r < n) C[(size_t)r*NC + c] = (CT)(acc[rt][ct][i] + bv);
        }
      }
    }
  }
}

// ---------------- Aggregation: 16 lanes per dst node, 8 fp16 feats (16 B) per lane ----------------

template<int MODE, bool OUTH>
__global__ __launch_bounds__(TPB) void agg_h(const __half* __restrict__ xh, const float* __restrict__ resf,
                                             const float* __restrict__ dinv, const int* __restrict__ row_ptr,
                                             const int* __restrict__ csr_src, const float* __restrict__ bias,
                                             void* __restrict__ outp, int n){
  int g = (int)((blockIdx.x * (unsigned)TPB + threadIdx.x) >> 4);
  if (g >= n) return;
  int lane = threadIdx.x & 15;
  float di = dinv[g];
  int beg = row_ptr[g], end = row_ptr[g+1];

  float accA[8], accB[8];
  #pragma unroll
  for (int i = 0; i < 8; ++i){ accA[i] = 0.f; accB[i] = 0.f; }

  for (int base = beg; base < end; base += 16){
    int m = end - base; if (m > 16) m = 16;
    int   sl = (lane < m) ? csr_src[base + lane] : 0;
    float cl = (lane < m) ? dinv[sl] * di : 0.f;
    int mm = (m + 1) & ~1;
    for (int j = 0; j < mm; j += 2){
      int   s0 = __shfl(sl, j,   16), s1 = __shfl(sl, j+1, 16);
      float c0 = __shfl(cl, j,   16), c1 = __shfl(cl, j+1, 16);
      uint4 u0 = *(const uint4*)(xh + (size_t)s0 * 128 + lane * 8);
      uint4 u1 = *(const uint4*)(xh + (size_t)s1 * 128 + lane * 8);
      const __half2* h0 = (const __half2*)&u0;
      const __half2* h1 = (const __half2*)&u1;
      #pragma unroll
      for (int i = 0; i < 4; ++i){
        float2 f0 = __half22float2(h0[i]);
        float2 f1 = __half22float2(h1[i]);
        accA[2*i]   = fmaf(c0, f0.x, accA[2*i]);
        accA[2*i+1] = fmaf(c0, f0.y, accA[2*i+1]);
        accB[2*i]   = fmaf(c1, f1.x, accB[2*i]);
        accB[2*i+1] = fmaf(c1, f1.y, accB[2*i+1]);
      }
    }
  }
  // self loop
  {
    float sc = 2.0f * di * di;
    uint4 u = *(const uint4*)(xh + (size_t)g * 128 + lane * 8);
    const __half2* h = (const __half2*)&u;
    #pragma unroll
    for (int i = 0; i < 4; ++i){
      float2 f = __half22float2(h[i]);
      accA[2*i]   = fmaf(sc, f.x, accA[2*i]);
      accA[2*i+1] = fmaf(sc, f.y, accA[2*i+1]);
    }
  }
  #pragma unroll
  for (int i = 0; i < 8; ++i) accA[i] += accB[i];

  if (MODE != 2){
    float4 b0 = *(const float4*)(bias + lane*8);
    float4 b1 = *(const float4*)(bias + lane*8 + 4);
    accA[0]+=b0.x; accA[1]+=b0.y; accA[2]+=b0.z; accA[3]+=b0.w;
    accA[4]+=b1.x; accA[5]+=b1.y; accA[6]+=b1.z; accA[7]+=b1.w;
  }
  if (MODE == 1){
    float4 r0 = *(const float4*)(resf + (size_t)g*128 + lane*8);
    float4 r1 = *(const float4*)(resf + (size_t)g*128 + lane*8 + 4);
    accA[0]+=r0.x; accA[1]+=r0.y; accA[2]+=r0.z; accA[3]+=r0.w;
    accA[4]+=r1.x; accA[5]+=r1.y; accA[6]+=r1.z; accA[7]+=r1.w;
  }
  if (MODE != 2){
    #pragma unroll
    for (int i = 0; i < 8; ++i) accA[i] = gelu_erf(accA[i]);
  }
  if (OUTH){
    __half hv[8];
    #pragma unroll
    for (int i = 0; i < 8; ++i) hv[i] = __float2half(accA[i]);
    *(uint4*)((__half*)outp + (size_t)g*128 + lane*8) = *(const uint4*)hv;
  } else {
    float* op = (float*)outp + (size_t)g*128 + lane*8;
    *(float4*)op       = make_float4(accA[0],accA[1],accA[2],accA[3]);
    *(float4*)(op + 4) = make_float4(accA[4],accA[5],accA[6],accA[7]);
  }
}

// ---------------- launch ----------------

extern "C" void kernel_launch(void* const* d_in, const int* in_sizes, int n_in,
                              void* d_out, int out_size, void* d_ws, size_t ws_size,
                              hipStream_t stream){
  const float* x  = (const float*)d_in[0];
  const int*   ei = (const int*)d_in[1];
  const float* W0 = (const float*)d_in[2];
  const float* b0 = (const float*)d_in[3];
  const float* W1 = (const float*)d_in[4];
  const float* b1 = (const float*)d_in[5];
  const float* W2 = (const float*)d_in[6];
  const float* b2 = (const float*)d_in[7];
  const float* W3 = (const float*)d_in[8];
  const float* b3 = (const float*)d_in[9];
  float* out = (float*)d_out;

  const int N = in_sizes[0] / 128;
  const int E = in_sizes[1] / 2;
  const int* src = ei;
  const int* dst = ei + E;

  char* ws = (char*)d_ws;
  size_t off = 0;
  auto alloc = [&](size_t bytes) -> void* {
    void* p = ws + off;
    off += (bytes + 255) & ~(size_t)255;
    return p;
  };
  __half* xw_h  = (__half*)alloc((size_t)N * 128 * 2);
  float*  gA    = (float*) alloc((size_t)N * 128 * 4);
  float*  gB    = (float*) alloc((size_t)N * 128 * 4);
  __half* gAh   = (__half*)alloc((size_t)N * 128 * 2);
  int* csr      = (int*)   alloc((size_t)E * 4);
  int* row_ptr  = (int*)   alloc((size_t)(N + 1) * 4);
  int* deg      = (int*)   alloc((size_t)N * 4);
  int* cursor   = (int*)   alloc((size_t)N * 4);
  float* dnv    = (float*) alloc((size_t)N * 4);
  int nb = (N + TPB - 1) / TPB;
  int* bsums    = (int*)   alloc((size_t)nb * 4);
  const int WTOT = 3*16384 + 48*128;
  unsigned short* Wh = (unsigned short*)alloc((size_t)WTOT * 2);
  unsigned short* Wl = (unsigned short*)alloc((size_t)WTOT * 2);
  (void)ws_size; (void)n_in; (void)out_size;

  hipMemsetAsync(deg, 0, (size_t)N * 4, stream);

  int ebl = (E + TPB - 1) / TPB;
  convW_all<<<(WTOT + TPB - 1)/TPB, TPB, 0, stream>>>(W0, W1, W2, W3, Wh, Wl);
  deg_kernel<<<ebl, TPB, 0, stream>>>(dst, deg, E);
  scan1<<<nb, TPB, 0, stream>>>(deg, row_ptr, bsums, dnv, N);
  scan2p<<<1, 1024, 0, stream>>>(bsums, nb);
  scan3<<<nb, TPB, 0, stream>>>(row_ptr, cursor, bsums, N, E);
  fill_kernel<<<ebl, TPB, 0, stream>>>(src, dst, cursor, csr, E);

  int gblocks = (N + 127) / 128;
  int ablocks = ((size_t)N * 16 + TPB - 1) / TPB;

  const unsigned short* W0h = Wh,          *W0l = Wl;
  const unsigned short* W1h = Wh + 16384,  *W1l = Wl + 16384;
  const unsigned short* W2h = Wh + 32768,  *W2l = Wl + 32768;
  const unsigned short* W3h = Wh + 49152,  *W3l = Wl + 49152;

  // L0: gA = gelu(conv(x))
  gemm_mfma<8,128,false,__half><<<gblocks, TPB, 0, stream>>>(x, W0h, W0l, nullptr, xw_h, N);
  agg_h<0,false><<<ablocks, TPB, 0, stream>>>(xw_h, nullptr, dnv, row_ptr, csr, b0, gA, N);
  // L1: gB = gelu(gA + conv(gA))
  gemm_mfma<8,128,false,__half><<<gblocks, TPB, 0, stream>>>(gA, W1h, W1l, nullptr, xw_h, N);
  agg_h<1,false><<<ablocks, TPB, 0, stream>>>(xw_h, gA, dnv, row_ptr, csr, b1, gB, N);
  // L2: gAh = gelu(gB + conv(gB))  (fp16 out, feeds gather-only consumer)
  gemm_mfma<8,128,false,__half><<<gblocks, TPB, 0, stream>>>(gB, W2h, W2l, nullptr, xw_h, N);
  agg_h<1,true><<<ablocks, TPB, 0, stream>>>(xw_h, gB, dnv, row_ptr, csr, b2, gAh, N);
  // L3: out = Agg(gAh) @ W3 + b3
  agg_h<2,false><<<ablocks, TPB, 0, stream>>>(gAh, nullptr, dnv, row_ptr, csr, nullptr, gA, N);
  gemm_mfma<3,40,true,float><<<gblocks, TPB, 0, stream>>>(gA, W3h, W3l, b3, out, N);
}

// Round 5
// 704.831 us; speedup vs baseline: 1.0460x; 1.0460x over previous
//
#include <hip/hip_runtime.h>
#include <hip/hip_fp16.h>
#include <math.h>

#define TPB 256

typedef short  bf16x8 __attribute__((ext_vector_type(8)));
typedef float  f32x4  __attribute__((ext_vector_type(4)));

__device__ __forceinline__ float gelu_erf(float x){
  return 0.5f * x * (1.0f + erff(x * 0.70710678118654752440f));
}

__device__ __forceinline__ unsigned short f2bf(float f){
  union { float f; unsigned u; } v; v.f = f;
  unsigned r = v.u + 0x7fff + ((v.u >> 16) & 1);
  return (unsigned short)(r >> 16);
}
__device__ __forceinline__ float bf2f(unsigned short h){
  union { unsigned u; float f; } v; v.u = ((unsigned)h) << 16; return v.f;
}

// ---------------- CSR build ----------------

__global__ __launch_bounds__(TPB) void deg_kernel(const int* __restrict__ dst, int* __restrict__ deg, int E){
  int i = blockIdx.x * TPB + threadIdx.x;
  if (i < E) atomicAdd(&deg[dst[i]], 1);
}

// block-local exclusive scan of deg -> row_ptr; block sums -> bsums; also dinv
__global__ __launch_bounds__(TPB) void scan1(const int* __restrict__ deg, int* __restrict__ row_ptr,
                                             int* __restrict__ bsums, float* __restrict__ dinv, int n){
  int gid = blockIdx.x * TPB + threadIdx.x;
  int v = (gid < n) ? deg[gid] : 0;
  if (gid < n) dinv[gid] = rsqrtf((float)v + 2.0f);
  int lane = threadIdx.x & 63;
  int wid  = threadIdx.x >> 6;
  int x = v;
  #pragma unroll
  for (int off = 1; off < 64; off <<= 1){
    int y = __shfl_up(x, off);
    if (lane >= off) x += y;
  }
  __shared__ int wtot[TPB/64];
  __shared__ int woff[TPB/64];
  if (lane == 63) wtot[wid] = x;
  __syncthreads();
  if (threadIdx.x == 0){
    int s = 0;
    #pragma unroll
    for (int i = 0; i < TPB/64; ++i){ woff[i] = s; s += wtot[i]; }
    bsums[blockIdx.x] = s;
  }
  __syncthreads();
  if (gid < n) row_ptr[gid] = x - v + woff[wid];
}

// parallel single-block exclusive scan of block sums (nb <= 1024)
__global__ __launch_bounds__(1024) void scan2p(int* __restrict__ bsums, int nb){
  __shared__ int tmp[1024];
  int t = threadIdx.x;
  int v = (t < nb) ? bsums[t] : 0;
  int x = v;
  tmp[t] = x;
  __syncthreads();
  #pragma unroll
  for (int off = 1; off < 1024; off <<= 1){
    int y = (t >= off) ? tmp[t - off] : 0;
    __syncthreads();
    x += y;
    tmp[t] = x;
    __syncthreads();
  }
  if (t < nb) bsums[t] = x - v;   // exclusive
}

__global__ __launch_bounds__(TPB) void scan3(int* __restrict__ row_ptr, int* __restrict__ cursor,
                                             const int* __restrict__ boffs, int n, int E){
  int gid = blockIdx.x * TPB + threadIdx.x;
  if (gid < n){
    int v = row_ptr[gid] + boffs[blockIdx.x];
    row_ptr[gid] = v;
    cursor[gid] = v;
  }
  if (gid == 0) row_ptr[n] = E;
}

// XCD-partitioned CSR fill. Blocks with blockIdx%8==g handle dst range g only,
// so the scattered csr_src stores for a given 800KB region are issued (heuristically)
// from a single XCD: its L2 accumulates ~16 dirty dwords/line and evicts once,
// instead of 1.6M partial-line (64B) evictions (R3/R4: WRITE_SIZE ~105-108MB).
__global__ __launch_bounds__(TPB) void fill_part(const int* __restrict__ src, const int* __restrict__ dst,
                                                 int* __restrict__ cursor, int* __restrict__ csr_src,
                                                 int E, int rstep, int G){
  int g = blockIdx.x & 7;          // XCD heuristic (perf-only)
  int m = blockIdx.x >> 3;         // chunk id in [0,G)
  int lo = g * rstep, hi = lo + rstep;
  long b0 = (long)m * E / G, b1 = (long)(m + 1) * E / G;
  for (long i = b0 + threadIdx.x; i < b1; i += TPB){
    int d = dst[i];
    if (d >= lo && d < hi){
      int pos = atomicAdd(&cursor[d], 1);
      csr_src[pos] = src[i];
    }
  }
}

// ---------------- W split/transpose: fp32 -> bf16 hi/lo, transposed [col][k] ----------------

__global__ __launch_bounds__(TPB) void convW_all(const float* __restrict__ W0, const float* __restrict__ W1,
                                                 const float* __restrict__ W2, const float* __restrict__ W3,
                                                 unsigned short* __restrict__ Wh, unsigned short* __restrict__ Wl){
  int gid = blockIdx.x * TPB + threadIdx.x;
  if (gid < 3*16384){
    int which = gid >> 14, idx = gid & 16383;
    int c = idx >> 7, k = idx & 127;
    const float* W = (which == 0) ? W0 : (which == 1) ? W1 : W2;
    float f = W[k*128 + c];
    unsigned short h = f2bf(f);
    unsigned short l = f2bf(f - bf2f(h));
    Wh[gid] = h; Wl[gid] = l;
  } else if (gid < 3*16384 + 48*128){
    int idx = gid - 3*16384;
    int c = idx >> 7, k = idx & 127;
    float f = (c < 40) ? W3[k*40 + c] : 0.f;
    unsigned short h = f2bf(f);
    unsigned short l = f2bf(f - bf2f(h));
    Wh[gid] = h; Wl[gid] = l;
  }
}

// ---------------- MFMA GEMM: C[N x NC] = A[N x 128] @ W[128 x NC] (+bias) ----------------

template<int NCT, int NC, bool BIAS, typename CT>
__global__ __launch_bounds__(TPB) void gemm_mfma(const float* __restrict__ A,
                                                 const unsigned short* __restrict__ Wh,
                                                 const unsigned short* __restrict__ Wl,
                                                 const float* __restrict__ bias,
                                                 CT* __restrict__ C, int n){
  int wave = threadIdx.x >> 6;
  int lane = threadIdx.x & 63;
  int q    = lane >> 4;
  int m16  = lane & 15;
  int r0   = blockIdx.x * 128 + wave * 32;

  f32x4 acc[2][NCT];
  #pragma unroll
  for (int rt = 0; rt < 2; ++rt)
    #pragma unroll
    for (int ct = 0; ct < NCT; ++ct)
      acc[rt][ct] = (f32x4){0.f, 0.f, 0.f, 0.f};

  for (int k0 = 0; k0 < 128; k0 += 32){
    bf16x8 ah[2], al[2];
    #pragma unroll
    for (int rt = 0; rt < 2; ++rt){
      int r = r0 + rt*16 + m16;
      if (r > n-1) r = n-1;
      const float* ap = A + (size_t)r*128 + k0 + q*8;
      float4 f0 = *(const float4*)(ap);
      float4 f1 = *(const float4*)(ap + 4);
      float fv[8] = {f0.x, f0.y, f0.z, f0.w, f1.x, f1.y, f1.z, f1.w};
      #pragma unroll
      for (int j = 0; j < 8; ++j){
        unsigned short h = f2bf(fv[j]);
        unsigned short l = f2bf(fv[j] - bf2f(h));
        ah[rt][j] = (short)h;
        al[rt][j] = (short)l;
      }
    }
    #pragma unroll
    for (int ct = 0; ct < NCT; ++ct){
      int c = ct*16 + m16;
      const unsigned short* ph = Wh + (size_t)c*128 + k0 + q*8;
      const unsigned short* pl = Wl + (size_t)c*128 + k0 + q*8;
      bf16x8 bh = *(const bf16x8*)ph;
      bf16x8 bl = *(const bf16x8*)pl;
      #pragma unroll
      for (int rt = 0; rt < 2; ++rt){
        acc[rt][ct] = __builtin_amdgcn_mfma_f32_16x16x32_bf16(ah[rt], bh, acc[rt][ct], 0, 0, 0);
        acc[rt][ct] = __builtin_amdgcn_mfma_f32_16x16x32_bf16(ah[rt], bl, acc[rt][ct], 0, 0, 0);
        acc[rt][ct] = __builtin_amdgcn_mfma_f32_16x16x32_bf16(al[rt], bh, acc[rt][ct], 0, 0, 0);
      }
    }
  }
  #pragma unroll
  for (int rt = 0; rt < 2; ++rt){
    #pragma unroll
    for (int ct = 0; ct < NCT; ++ct){
      int c = ct*16 + m16;
      if (c < NC){
        float bv = BIAS ? bias[c] : 0.f;
        #pragma unroll
        for (int i = 0; i < 4; ++i){
          int r = r0 + rt*16 + q*4 + i;
          if (r < n) C[(size_t)r*NC + c] = (CT)(acc[rt][ct][i] + bv);
        }
      }
    }
  }
}

// ---------------- Aggregation: 16 lanes per dst node, 8 fp16 feats (16 B) per lane ----------------

template<int MODE, bool OUTH>
__global__ __launch_bounds__(TPB) void agg_h(const __half* __restrict__ xh, const float* __restrict__ resf,
                                             const float* __restrict__ dinv, const int* __restrict__ row_ptr,
                                             const int* __restrict__ csr_src, const float* __restrict__ bias,
                                             void* __restrict__ outp, int n){
  int g = (int)((blockIdx.x * (unsigned)TPB + threadIdx.x) >> 4);
  if (g >= n) return;
  int lane = threadIdx.x & 15;
  float di = dinv[g];
  int beg = row_ptr[g], end = row_ptr[g+1];

  float accA[8], accB[8];
  #pragma unroll
  for (int i = 0; i < 8; ++i){ accA[i] = 0.f; accB[i] = 0.f; }

  for (int base = beg; base < end; base += 16){
    int m = end - base; if (m > 16) m = 16;
    int   sl = (lane < m) ? csr_src[base + lane] : 0;
    float cl = (lane < m) ? dinv[sl] * di : 0.f;
    int mm = (m + 1) & ~1;
    for (int j = 0; j < mm; j += 2){
      int   s0 = __shfl(sl, j,   16), s1 = __shfl(sl, j+1, 16);
      float c0 = __shfl(cl, j,   16), c1 = __shfl(cl, j+1, 16);
      uint4 u0 = *(const uint4*)(xh + (size_t)s0 * 128 + lane * 8);
      uint4 u1 = *(const uint4*)(xh + (size_t)s1 * 128 + lane * 8);
      const __half2* h0 = (const __half2*)&u0;
      const __half2* h1 = (const __half2*)&u1;
      #pragma unroll
      for (int i = 0; i < 4; ++i){
        float2 f0 = __half22float2(h0[i]);
        float2 f1 = __half22float2(h1[i]);
        accA[2*i]   = fmaf(c0, f0.x, accA[2*i]);
        accA[2*i+1] = fmaf(c0, f0.y, accA[2*i+1]);
        accB[2*i]   = fmaf(c1, f1.x, accB[2*i]);
        accB[2*i+1] = fmaf(c1, f1.y, accB[2*i+1]);
      }
    }
  }
  // self loop
  {
    float sc = 2.0f * di * di;
    uint4 u = *(const uint4*)(xh + (size_t)g * 128 + lane * 8);
    const __half2* h = (const __half2*)&u;
    #pragma unroll
    for (int i = 0; i < 4; ++i){
      float2 f = __half22float2(h[i]);
      accA[2*i]   = fmaf(sc, f.x, accA[2*i]);
      accA[2*i+1] = fmaf(sc, f.y, accA[2*i+1]);
    }
  }
  #pragma unroll
  for (int i = 0; i < 8; ++i) accA[i] += accB[i];

  if (MODE != 2){
    float4 b0 = *(const float4*)(bias + lane*8);
    float4 b1 = *(const float4*)(bias + lane*8 + 4);
    accA[0]+=b0.x; accA[1]+=b0.y; accA[2]+=b0.z; accA[3]+=b0.w;
    accA[4]+=b1.x; accA[5]+=b1.y; accA[6]+=b1.z; accA[7]+=b1.w;
  }
  if (MODE == 1){
    float4 r0 = *(const float4*)(resf + (size_t)g*128 + lane*8);
    float4 r1 = *(const float4*)(resf + (size_t)g*128 + lane*8 + 4);
    accA[0]+=r0.x; accA[1]+=r0.y; accA[2]+=r0.z; accA[3]+=r0.w;
    accA[4]+=r1.x; accA[5]+=r1.y; accA[6]+=r1.z; accA[7]+=r1.w;
  }
  if (MODE != 2){
    #pragma unroll
    for (int i = 0; i < 8; ++i) accA[i] = gelu_erf(accA[i]);
  }
  if (OUTH){
    __half hv[8];
    #pragma unroll
    for (int i = 0; i < 8; ++i) hv[i] = __float2half(accA[i]);
    *(uint4*)((__half*)outp + (size_t)g*128 + lane*8) = *(const uint4*)hv;
  } else {
    float* op = (float*)outp + (size_t)g*128 + lane*8;
    *(float4*)op       = make_float4(accA[0],accA[1],accA[2],accA[3]);
    *(float4*)(op + 4) = make_float4(accA[4],accA[5],accA[6],accA[7]);
  }
}

// ---------------- launch ----------------

extern "C" void kernel_launch(void* const* d_in, const int* in_sizes, int n_in,
                              void* d_out, int out_size, void* d_ws, size_t ws_size,
                              hipStream_t stream){
  const float* x  = (const float*)d_in[0];
  const int*   ei = (const int*)d_in[1];
  const float* W0 = (const float*)d_in[2];
  const float* b0 = (const float*)d_in[3];
  const float* W1 = (const float*)d_in[4];
  const float* b1 = (const float*)d_in[5];
  const float* W2 = (const float*)d_in[6];
  const float* b2 = (const float*)d_in[7];
  const float* W3 = (const float*)d_in[8];
  const float* b3 = (const float*)d_in[9];
  float* out = (float*)d_out;

  const int N = in_sizes[0] / 128;
  const int E = in_sizes[1] / 2;
  const int* src = ei;
  const int* dst = ei + E;

  char* ws = (char*)d_ws;
  size_t off = 0;
  auto alloc = [&](size_t bytes) -> void* {
    void* p = ws + off;
    off += (bytes + 255) & ~(size_t)255;
    return p;
  };
  __half* xw_h  = (__half*)alloc((size_t)N * 128 * 2);
  float*  gA    = (float*) alloc((size_t)N * 128 * 4);
  float*  gB    = (float*) alloc((size_t)N * 128 * 4);
  __half* gAh   = (__half*)alloc((size_t)N * 128 * 2);
  int* csr      = (int*)   alloc((size_t)E * 4);
  int* row_ptr  = (int*)   alloc((size_t)(N + 1) * 4);
  int* deg      = (int*)   alloc((size_t)N * 4);
  int* cursor   = (int*)   alloc((size_t)N * 4);
  float* dnv    = (float*) alloc((size_t)N * 4);
  int nb = (N + TPB - 1) / TPB;
  int* bsums    = (int*)   alloc((size_t)nb * 4);
  const int WTOT = 3*16384 + 48*128;
  unsigned short* Wh = (unsigned short*)alloc((size_t)WTOT * 2);
  unsigned short* Wl = (unsigned short*)alloc((size_t)WTOT * 2);
  (void)ws_size; (void)n_in; (void)out_size;

  hipMemsetAsync(deg, 0, (size_t)N * 4, stream);

  int ebl = (E + TPB - 1) / TPB;
  convW_all<<<(WTOT + TPB - 1)/TPB, TPB, 0, stream>>>(W0, W1, W2, W3, Wh, Wl);
  deg_kernel<<<ebl, TPB, 0, stream>>>(dst, deg, E);
  scan1<<<nb, TPB, 0, stream>>>(deg, row_ptr, bsums, dnv, N);
  scan2p<<<1, 1024, 0, stream>>>(bsums, nb);
  scan3<<<nb, TPB, 0, stream>>>(row_ptr, cursor, bsums, N, E);
  // XCD-partitioned fill: 8 groups x G chunks
  {
    const int G = 128;
    int rstep = (N + 7) / 8;
    fill_part<<<8 * G, TPB, 0, stream>>>(src, dst, cursor, csr, E, rstep, G);
  }

  int gblocks = (N + 127) / 128;
  int ablocks = ((size_t)N * 16 + TPB - 1) / TPB;

  const unsigned short* W0h = Wh,          *W0l = Wl;
  const unsigned short* W1h = Wh + 16384,  *W1l = Wl + 16384;
  const unsigned short* W2h = Wh + 32768,  *W2l = Wl + 32768;
  const unsigned short* W3h = Wh + 49152,  *W3l = Wl + 49152;

  // L0: gA = gelu(conv(x))
  gemm_mfma<8,128,false,__half><<<gblocks, TPB, 0, stream>>>(x, W0h, W0l, nullptr, xw_h, N);
  agg_h<0,false><<<ablocks, TPB, 0, stream>>>(xw_h, nullptr, dnv, row_ptr, csr, b0, gA, N);
  // L1: gB = gelu(gA + conv(gA))
  gemm_mfma<8,128,false,__half><<<gblocks, TPB, 0, stream>>>(gA, W1h, W1l, nullptr, xw_h, N);
  agg_h<1,false><<<ablocks, TPB, 0, stream>>>(xw_h, gA, dnv, row_ptr, csr, b1, gB, N);
  // L2: gAh = gelu(gB + conv(gB))  (fp16 out, feeds gather-only consumer)
  gemm_mfma<8,128,false,__half><<<gblocks, TPB, 0, stream>>>(gB, W2h, W2l, nullptr, xw_h, N);
  agg_h<1,true><<<ablocks, TPB, 0, stream>>>(xw_h, gB, dnv, row_ptr, csr, b2, gAh, N);
  // L3: out = Agg(gAh) @ W3 + b3
  agg_h<2,false><<<ablocks, TPB, 0, stream>>>(gAh, nullptr, dnv, row_ptr, csr, nullptr, gA, N);
  gemm_mfma<3,40,true,float><<<gblocks, TPB, 0, stream>>>(gA, W3h, W3l, b3, out, N);
}